// Round 10
// baseline (474.713 us; speedup 1.0000x reference)
//
#include <hip/hip_runtime.h>

// Max-unpooling scatter-add, one-level coarse radix (1024 buckets) with LDS
// batch-sort, then merged sort2+accumulate (pairs in registers, 4 x 128 KB
// LDS window sweeps). No global atomics.
//   out = zeros(total); out[ind[i]] += x[i]
// N = 2^25 pairs, OUT = 2^27 floats (536.9 MB).
//
// R10: (1) XCD-grouped segment placement in P1: tile t's segment sits at
// position p(t)=(t%8)*128+t/8 within each bucket region, so the ~32
// concurrently-resident blocks of an XCD write CONTIGUOUS segments ->
// partial cache lines merge in that XCD's L2 instead of thrashing HBM
// (blocks dispatch round-robin across 8 XCDs; per-XCD L2s not coherent).
// (2) waccum sweeps 4 x 128 KB LDS windows instead of 8 x 64 KB: halves the
// predicated ds_add issue inflation (lane density 12.5% -> 25%).

typedef float    f32x4 __attribute__((ext_vector_type(4)));
typedef int      i32x4 __attribute__((ext_vector_type(4)));
typedef unsigned u32x2 __attribute__((ext_vector_type(2)));

#define N_TOT   (1 << 25)     // input pairs
#define OUT_TOT (1 << 27)     // output floats
#define T1      1024          // scatter tiles
#define PT      (N_TOT / T1)  // 32768 pairs/tile
#define PT4     (PT / 4)      // 8192 vec4/tile
#define NB1     1024          // coarse buckets
#define CSH     17            // coarse = idx >> 17  (window 2^17 floats = 512 KB)
#define SSH2    15            // sweep selector = (idx >> 15) & 3
#define NSUB2   4
#define WFL2    32768         // floats per sweep window (128 KB LDS)
#define BATCH   16384         // pairs per sort batch (128 KB LDS sbuf)
#define KREG    36            // pairs/thread in k_waccum (1024 thr: cap 36864)

// XCD-grouping permutation: segment position of tile t within each bucket.
// Blocks b=k,k+8,k+16,.. (XCD k, dispatched round-robin) get contiguous p.
__device__ __forceinline__ unsigned tile_pos(unsigned t) {
  return ((t & 7u) << 7) | (t >> 3);   // (t%8)*128 + t/8, T1=1024
}

// ---- K1: per-tile coarse histogram (u16), stored at permuted row p(t) ----
__global__ __launch_bounds__(1024) void k_hist(const int* __restrict__ ind,
                                               unsigned short* __restrict__ M1) {
  __shared__ unsigned h[NB1];
  const int t = blockIdx.x;
  h[threadIdx.x] = 0;
  __syncthreads();
  const i32x4* p = reinterpret_cast<const i32x4*>(ind) + (size_t)t * PT4;
  for (int k = threadIdx.x; k < PT4; k += 1024) {
    i32x4 id = p[k];   // cacheable: ind re-read by scatter1 (L3 reuse)
    atomicAdd(&h[(unsigned)id.x >> CSH], 1u);
    atomicAdd(&h[(unsigned)id.y >> CSH], 1u);
    atomicAdd(&h[(unsigned)id.z >> CSH], 1u);
    atomicAdd(&h[(unsigned)id.w >> CSH], 1u);
  }
  __syncthreads();
  M1[(size_t)tile_pos(t) * NB1 + threadIdx.x] = (unsigned short)h[threadIdx.x];
}

// ---- K2: per-bucket exclusive scan of M1 over (permuted) tiles ----
__global__ __launch_bounds__(256) void k_colscan1(const unsigned short* __restrict__ M1,
                                                  unsigned* __restrict__ Mscan1,
                                                  unsigned* __restrict__ colsum) {
  __shared__ unsigned part[256];
  const int b = blockIdx.x;
  const int tid = threadIdx.x;
  unsigned v[4];
  unsigned s = 0;
  #pragma unroll
  for (int j = 0; j < 4; ++j) {
    v[j] = M1[(size_t)(4 * tid + j) * NB1 + b];
    s += v[j];
  }
  part[tid] = s;
  __syncthreads();
  for (int off = 1; off < 256; off <<= 1) {
    unsigned add = (tid >= off) ? part[tid - off] : 0u;
    __syncthreads();
    part[tid] += add;
    __syncthreads();
  }
  unsigned exc = part[tid] - s;
  #pragma unroll
  for (int j = 0; j < 4; ++j) {
    Mscan1[(size_t)(4 * tid + j) * NB1 + b] = exc;
    exc += v[j];
  }
  if (tid == 255) colsum[b] = part[255];
}

// ---- K3: exclusive scan colsum[1024] -> cb[1025] ----
__global__ __launch_bounds__(256) void k_scancb(const unsigned* __restrict__ colsum,
                                                unsigned* __restrict__ cb) {
  __shared__ unsigned part[256];
  const int tid = threadIdx.x;
  unsigned loc[4];
  unsigned s = 0;
  #pragma unroll
  for (int j = 0; j < 4; ++j) { loc[j] = colsum[4 * tid + j]; s += loc[j]; }
  part[tid] = s;
  __syncthreads();
  for (int off = 1; off < 256; off <<= 1) {
    unsigned add = (tid >= off) ? part[tid - off] : 0u;
    __syncthreads();
    part[tid] += add;
    __syncthreads();
  }
  unsigned exc = part[tid] - s;
  #pragma unroll
  for (int j = 0; j < 4; ++j) { cb[4 * tid + j] = exc; exc += loc[j]; }
  if (tid == 255) cb[NB1] = part[255];  // == N_TOT
}

// ---- K4: coarse scatter with LDS batch-sort; XCD-grouped segment slots ----
__global__ __launch_bounds__(1024) void k_scatter1(const float* __restrict__ x,
                                                   const int* __restrict__ ind,
                                                   const unsigned* __restrict__ Mscan1,
                                                   const unsigned* __restrict__ cb,
                                                   u32x2* __restrict__ P1) {
  __shared__ u32x2    sbuf[BATCH];                      // 128 KB
  __shared__ unsigned hist[NB1], sbase[NB1], cur[NB1];  // 12 KB
  const int t = blockIdx.x;
  const i32x4* pi = reinterpret_cast<const i32x4*>(ind) + (size_t)t * PT4;
  const f32x4* pv = reinterpret_cast<const f32x4*>(x)  + (size_t)t * PT4;

  // Prefetch BOTH batches up-front (1 block/CU: overlap global reads with
  // batch-0's LDS sort + stores).
  i32x4 idx[2][4];
  f32x4 val[2][4];
  #pragma unroll
  for (int bt = 0; bt < 2; ++bt) {
    const int v0 = bt * (BATCH / 4);
    #pragma unroll
    for (int q = 0; q < 4; ++q) {
      idx[bt][q] = pi[v0 + q * 1024 + threadIdx.x];
      val[bt][q] = __builtin_nontemporal_load(pv + v0 + q * 1024 + threadIdx.x);
    }
  }
  cur[threadIdx.x] = cb[threadIdx.x] + Mscan1[(size_t)tile_pos(t) * NB1 + threadIdx.x];

  #pragma unroll
  for (int bt = 0; bt < 2; ++bt) {
    hist[threadIdx.x] = 0;
    __syncthreads();
    unsigned r[16];
    #pragma unroll
    for (int q = 0; q < 4; ++q) {
      r[4 * q + 0] = atomicAdd(&hist[(unsigned)idx[bt][q].x >> CSH], 1u);
      r[4 * q + 1] = atomicAdd(&hist[(unsigned)idx[bt][q].y >> CSH], 1u);
      r[4 * q + 2] = atomicAdd(&hist[(unsigned)idx[bt][q].z >> CSH], 1u);
      r[4 * q + 3] = atomicAdd(&hist[(unsigned)idx[bt][q].w >> CSH], 1u);
    }
    __syncthreads();
    if (threadIdx.x < 64) {   // exclusive scan of hist[1024]: 16 entries/lane
      const unsigned lane = threadIdx.x;
      unsigned h[16], sum = 0;
      #pragma unroll
      for (int j = 0; j < 16; ++j) { h[j] = hist[16 * lane + j]; sum += h[j]; }
      unsigned inc = sum;
      for (int off = 1; off < 64; off <<= 1) {
        unsigned o = __shfl_up(inc, off, 64);
        if (lane >= (unsigned)off) inc += o;
      }
      unsigned exc = inc - sum;
      #pragma unroll
      for (int j = 0; j < 16; ++j) { sbase[16 * lane + j] = exc; exc += h[j]; }
    }
    __syncthreads();
    #pragma unroll
    for (int q = 0; q < 4; ++q) {
      sbuf[sbase[(unsigned)idx[bt][q].x >> CSH] + r[4 * q + 0]] =
          (u32x2){__float_as_uint(val[bt][q].x), (unsigned)idx[bt][q].x};
      sbuf[sbase[(unsigned)idx[bt][q].y >> CSH] + r[4 * q + 1]] =
          (u32x2){__float_as_uint(val[bt][q].y), (unsigned)idx[bt][q].y};
      sbuf[sbase[(unsigned)idx[bt][q].z >> CSH] + r[4 * q + 2]] =
          (u32x2){__float_as_uint(val[bt][q].z), (unsigned)idx[bt][q].z};
      sbuf[sbase[(unsigned)idx[bt][q].w >> CSH] + r[4 * q + 3]] =
          (u32x2){__float_as_uint(val[bt][q].w), (unsigned)idx[bt][q].w};
    }
    __syncthreads();
    #pragma unroll
    for (int k = 0; k < BATCH / 1024; ++k) {   // 16 coalesced segment stores
      unsigned j = (unsigned)(k * 1024 + threadIdx.x);
      u32x2 q = sbuf[j];
      unsigned b = q.y >> CSH;
      P1[cur[b] + (j - sbase[b])] = q;   // cacheable: L2-merge + waccum re-read
    }
    __syncthreads();
    cur[threadIdx.x] += hist[threadIdx.x];
    __syncthreads();
  }
}

// ---- K5: merged sort2+accum. Pairs in regs, 4 x 128 KB LDS sweeps ----
__global__ __launch_bounds__(1024) void k_waccum(const u32x2* __restrict__ P1,
                                                 const unsigned* __restrict__ cb,
                                                 float* __restrict__ out) {
  __shared__ float w[WFL2];   // 128 KB
  const int c = blockIdx.x;
  const unsigned s = cb[c], e = cb[c + 1];
  const unsigned len = e - s;
  const u32x2* P = P1 + s;
  u32x2 p[KREG];
  #pragma unroll
  for (int k = 0; k < KREG; ++k) {
    unsigned j = (unsigned)(k * 1024) + threadIdx.x;
    if (j < len) {
      p[k] = P[j];
    } else {
      // harmless sentinel: adds 0.0f into sweep 0 at scattered slots
      p[k] = (u32x2){0u, ((unsigned)c << CSH) | (threadIdx.x & 16383u)};
    }
  }
  f32x4* w4 = reinterpret_cast<f32x4*>(w);
  for (int sub = 0; sub < NSUB2; ++sub) {
    for (int i = threadIdx.x; i < WFL2 / 4; i += 1024) w4[i] = (f32x4){0.f, 0.f, 0.f, 0.f};
    __syncthreads();
    #pragma unroll
    for (int k = 0; k < KREG; ++k) {
      if (((p[k].y >> SSH2) & (NSUB2 - 1)) == (unsigned)sub)
        atomicAdd(&w[p[k].y & (WFL2 - 1)], __uint_as_float(p[k].x));  // ds_add_f32
    }
    // tail safety (len > KREG*1024: ~never for this input, correct always)
    for (unsigned j = (unsigned)(KREG * 1024) + threadIdx.x; j < len; j += 1024) {
      u32x2 q = P[j];
      if (((q.y >> SSH2) & (NSUB2 - 1)) == (unsigned)sub)
        atomicAdd(&w[q.y & (WFL2 - 1)], __uint_as_float(q.x));
    }
    __syncthreads();
    f32x4* o = reinterpret_cast<f32x4*>(out + ((size_t)c << CSH) + ((size_t)sub << SSH2));
    for (int i = threadIdx.x; i < WFL2 / 4; i += 1024)
      __builtin_nontemporal_store(w4[i], o + i);
    __syncthreads();
  }
}

// ---- Fallback: plain atomic scatter (measured ~1.77 ms) ----
__global__ __launch_bounds__(256) void unpool_scatter_kernel(
    const float* __restrict__ x, const int* __restrict__ ind,
    float* __restrict__ out, int n4) {
  int i = blockIdx.x * blockDim.x + threadIdx.x;
  if (i >= n4) return;
  f32x4 v  = reinterpret_cast<const f32x4*>(x)[i];
  i32x4 id = reinterpret_cast<const i32x4*>(ind)[i];
  unsafeAtomicAdd(&out[id.x], v.x);
  unsafeAtomicAdd(&out[id.y], v.y);
  unsafeAtomicAdd(&out[id.z], v.z);
  unsafeAtomicAdd(&out[id.w], v.w);
}

extern "C" void kernel_launch(void* const* d_in, const int* in_sizes, int n_in,
                              void* d_out, int out_size, void* d_ws, size_t ws_size,
                              hipStream_t stream) {
  const float* x   = (const float*)d_in[0];
  const int*   ind = (const int*)d_in[1];
  float*       out = (float*)d_out;
  const int n = in_sizes[0];

  // ws layout: M1(u16) | Mscan1(u32) | colsum | cb | P1  (~275 MB)
  const size_t szM1  = (size_t)T1 * NB1 * sizeof(unsigned short);  // 2 MB
  const size_t szMs  = (size_t)T1 * NB1 * sizeof(unsigned);        // 4 MB
  const size_t szCs  = ((size_t)NB1 * sizeof(unsigned) + 255) & ~(size_t)255;
  const size_t szCb  = ((size_t)(NB1 + 1) * sizeof(unsigned) + 255) & ~(size_t)255;
  const size_t szP1  = (size_t)N_TOT * sizeof(u32x2);              // 268.4 MB
  const size_t need  = szM1 + szMs + szCs + szCb + szP1;

  const bool shape_ok = (n == N_TOT) && (out_size == OUT_TOT);

  if (!shape_ok || ws_size < need) {
    (void)hipMemsetAsync(d_out, 0, (size_t)out_size * sizeof(float), stream);
    const int n4 = n / 4;
    unpool_scatter_kernel<<<(n4 + 255) / 256, 256, 0, stream>>>(x, ind, out, n4);
    return;
  }

  char* ws = (char*)d_ws;
  unsigned short* M1     = (unsigned short*)(ws);
  unsigned*       Mscan1 = (unsigned*)(ws + szM1);
  unsigned*       colsum = (unsigned*)(ws + szM1 + szMs);
  unsigned*       cb     = (unsigned*)(ws + szM1 + szMs + szCs);
  u32x2*          P1     = (u32x2*)(ws + szM1 + szMs + szCs + szCb);

  k_hist    <<<T1,  1024, 0, stream>>>(ind, M1);
  k_colscan1<<<NB1,  256, 0, stream>>>(M1, Mscan1, colsum);
  k_scancb  <<<1,    256, 0, stream>>>(colsum, cb);
  k_scatter1<<<T1,  1024, 0, stream>>>(x, ind, Mscan1, cb, P1);
  k_waccum  <<<NB1, 1024, 0, stream>>>(P1, cb, out);
  // Output fully covered by dense windows -> no memset needed.
}